// Round 3
// baseline (701.035 us; speedup 1.0000x reference)
//
#include <hip/hip_runtime.h>

#define TSTEPS 1000
#define NBATCH 4096
#define INF 22
#define HID 10
#define NCLS 4
#define UNROLL 4
#define NITER (TSTEPS / UNROLL)

// Wave layout: 4 batches x 16 lanes (j = lane&15, active j<10).
// Block: 256 threads = 4 waves = 16 batches. Grid: 4096/16 = 256 blocks.
// Weights live in per-lane registers (lane j holds row j of each W).
// x staged via wave-local LDS, prefetched one iter (4 steps) ahead.
// h broadcast inside 16-lane groups via ds_bpermute. No __syncthreads anywhere.

__launch_bounds__(256, 1)
__global__ void rnn_fused_kernel(const float* __restrict__ x,
                                 const float* __restrict__ Wih0, const float* __restrict__ bih0,
                                 const float* __restrict__ Whh0, const float* __restrict__ bhh0,
                                 const float* __restrict__ Wih1, const float* __restrict__ bih1,
                                 const float* __restrict__ Whh1, const float* __restrict__ bhh1,
                                 const float* __restrict__ Wlin, const float* __restrict__ blin,
                                 float* __restrict__ out)
{
    __shared__ __align__(16) float xs[4 * 4 * 4 * 24];  // [wave][b][ts][24 words] = 6 KB

    const int tid  = threadIdx.x;
    const int wave = tid >> 6;
    const int lane = tid & 63;
    const int bl   = lane >> 4;          // batch within wave (0..3)
    const int j    = lane & 15;          // hidden unit (active < 10)
    const int bg   = (int)blockIdx.x * 16 + wave * 4 + bl;

    // ---- per-lane weight registers ----
    const bool act = (j < HID);
    float w_ih0[INF], w_hh0[HID], w_ih1[HID], w_hh1[HID], w_lin[HID];
#pragma unroll
    for (int i = 0; i < INF; ++i) w_ih0[i] = act ? Wih0[j * INF + i] : 0.f;
#pragma unroll
    for (int i = 0; i < HID; ++i) w_hh0[i] = act ? Whh0[j * HID + i] : 0.f;
#pragma unroll
    for (int i = 0; i < HID; ++i) w_ih1[i] = act ? Wih1[j * HID + i] : 0.f;
#pragma unroll
    for (int i = 0; i < HID; ++i) w_hh1[i] = act ? Whh1[j * HID + i] : 0.f;
#pragma unroll
    for (int i = 0; i < HID; ++i) w_lin[i] = (j < NCLS) ? Wlin[j * HID + i] : 0.f;
    const float bias0 = act ? (bih0[j] + bhh0[j]) : 0.f;
    const float bias1 = act ? (bih1[j] + bhh1[j]) : 0.f;
    const float bout  = (j < NCLS) ? blin[j] : 0.f;

    // ---- bpermute byte addresses for 16-lane group broadcast ----
    int srcb[HID];
#pragma unroll
    for (int i = 0; i < HID; ++i) srcb[i] = ((lane & 48) + i) << 2;

    // ---- x staging map: float2 pair p = lane + 64q (q<3, p<176) ----
    // p -> b = p/44, r = p%44, ts = r/11, ip = r%11  (11 pairs per row of 22)
    int goff[3], loff[3];
    bool pm[3];
#pragma unroll
    for (int q = 0; q < 3; ++q) {
        int p = lane + 64 * q;
        pm[q] = (p < 176);
        int pp = pm[q] ? p : 0;
        int b = pp / 44, r = pp % 44, ts = r / 11, ip = r % 11;
        goff[q] = ((((int)blockIdx.x * 16 + wave * 4 + b) * 22000) + ts * 22 + 2 * ip) >> 1;
        loff[q] = (wave * 384 + b * 96 + ts * 24 + 2 * ip) >> 1;
    }
    const float2* __restrict__ x2 = (const float2*)x;
    float2* xs2 = (float2*)xs;

    // prologue: load iter 0's x into regs
    float2 r0[3];
#pragma unroll
    for (int q = 0; q < 3; ++q) r0[q] = pm[q] ? x2[goff[q]] : make_float2(0.f, 0.f);

    float h0s[HID], h1s[HID];
#pragma unroll
    for (int i = 0; i < HID; ++i) { h0s[i] = 0.f; h1s[i] = 0.f; }

    const int rbase = wave * 384 + bl * 96;

    for (int it = 0; it < NITER; ++it) {
        // write current iter's x regs to LDS
#pragma unroll
        for (int q = 0; q < 3; ++q)
            if (pm[q]) xs2[loff[q]] = r0[q];
        // issue next iter's loads (prefetch ~1 iter ahead)
        if (it + 1 < NITER) {
#pragma unroll
            for (int q = 0; q < 3; ++q) {
                goff[q] += 44;
                if (pm[q]) r0[q] = x2[goff[q]];
            }
        }
        // wave-local: DS ops are in-order per wave; wait for writes, order reads after
        asm volatile("s_waitcnt lgkmcnt(0)" ::: "memory");

#pragma unroll
        for (int ts = 0; ts < UNROLL; ++ts) {
            float xv[24];
#pragma unroll
            for (int v = 0; v < 6; ++v)
                *(float4*)&xv[v * 4] = *(const float4*)&xs[rbase + ts * 24 + v * 4];

            // ---- layer 0: h0 = relu(x.W_ih0[j] + h0_prev.W_hh0[j] + bias0) ----
            float s[4] = {bias0, 0.f, 0.f, 0.f};
#pragma unroll
            for (int i = 0; i < INF; ++i) s[i & 3] = fmaf(xv[i], w_ih0[i], s[i & 3]);
#pragma unroll
            for (int i = 0; i < HID; ++i) s[i & 3] = fmaf(h0s[i], w_hh0[i], s[i & 3]);
            float h0 = fmaxf((s[0] + s[1]) + (s[2] + s[3]), 0.f);

            // broadcast h0 across the 16-lane group
#pragma unroll
            for (int i = 0; i < HID; ++i)
                h0s[i] = __int_as_float(__builtin_amdgcn_ds_bpermute(srcb[i], __float_as_int(h0)));

            // ---- layer 1: h1 = relu(h0.W_ih1[j] + h1_prev.W_hh1[j] + bias1) ----
            float u[4] = {bias1, 0.f, 0.f, 0.f};
#pragma unroll
            for (int i = 0; i < HID; ++i) u[i & 3] = fmaf(h0s[i], w_ih1[i], u[i & 3]);
#pragma unroll
            for (int i = 0; i < HID; ++i) u[i & 3] = fmaf(h1s[i], w_hh1[i], u[i & 3]);
            float h1 = fmaxf((u[0] + u[1]) + (u[2] + u[3]), 0.f);

#pragma unroll
            for (int i = 0; i < HID; ++i)
                h1s[i] = __int_as_float(__builtin_amdgcn_ds_bpermute(srcb[i], __float_as_int(h1)));
        }
    }

    // ---- epilogue: logits[bg][j] = relu(h1_final) . W_lin[j] + b_lin[j] ----
    // h1 is already >= 0 (post-relu), F.relu is idempotent.
    if (j < NCLS) {
        float o0 = bout, o1 = 0.f;
#pragma unroll
        for (int i = 0; i < HID; i += 2) {
            o0 = fmaf(h1s[i], w_lin[i], o0);
            o1 = fmaf(h1s[i + 1], w_lin[i + 1], o1);
        }
        out[bg * NCLS + j] = o0 + o1;
    }
}

extern "C" void kernel_launch(void* const* d_in, const int* in_sizes, int n_in,
                              void* d_out, int out_size, void* d_ws, size_t ws_size,
                              hipStream_t stream) {
    const float* x    = (const float*)d_in[0];
    const float* Wih0 = (const float*)d_in[1];
    const float* bih0 = (const float*)d_in[2];
    const float* Whh0 = (const float*)d_in[3];
    const float* bhh0 = (const float*)d_in[4];
    const float* Wih1 = (const float*)d_in[5];
    const float* bih1 = (const float*)d_in[6];
    const float* Whh1 = (const float*)d_in[7];
    const float* bhh1 = (const float*)d_in[8];
    const float* Wlin = (const float*)d_in[9];
    const float* blin = (const float*)d_in[10];
    float* out = (float*)d_out;

    dim3 grid(NBATCH / 16);   // 256 blocks
    dim3 block(256);          // 4 waves x 4 batches
    hipLaunchKernelGGL(rnn_fused_kernel, grid, block, 0, stream,
                       x, Wih0, bih0, Whh0, bhh0, Wih1, bih1, Whh1, bhh1, Wlin, blin, out);
}